// Round 21
// baseline (44.368 us; speedup 1.0000x reference)
//
#include <hip/hip_runtime.h>
#include <hip/hip_bf16.h>

// Problem constants
#define IH 4096
#define IW 4096
#define KH 11
#define KW 11
#define OH (IH - KH + 1)   // 4086
#define OW (IW - KW + 1)   // 4086

// One wave (64 threads) per block; wave computes a 16x64 output strip
// (4 c-tiles of 16x16). It stages its own 26x80 input band -> ZERO barriers.
#define SROWS   26                 // 16 + 10 halo
#define TSTRIDE 84                 // bf16 row stride: li*42 words mod 32 = 16
                                   // distinct residues -> free 2-way (r11-r19)
#define NCHW    20                 // float4 chunks per row (80 cols)
#define WCHUNK  (SROWS * NCHW)     // 520
#define TILE_SHORTS (SROWS * TSTRIDE)  // 2184 -> 4368 B LDS per block

#define STRIPS_X 64
#define ROWS_Y   256               // 4096/16
#define NBLK     (STRIPS_X * ROWS_Y)   // 16384

typedef short bf16x4 __attribute__((ext_vector_type(4)));
typedef short bf16x8 __attribute__((ext_vector_type(8)));
typedef float f32x4  __attribute__((ext_vector_type(4)));

__device__ __forceinline__ short f2b(float f) {
    __hip_bfloat16 h = __float2bfloat16(f);   // RNE
    return __builtin_bit_cast(short, h);
}

// ---- setup kernel (r17-r20, verified): banded-Toeplitz B in global ----
// B_kh[k][j] = w[kh][k-j] (banded), stored [kh][j][k]: lane frag = 16B chunk.
__global__ void build_bmat(const float* __restrict__ w, short* __restrict__ bm) {
    const int tid = threadIdx.x;
#pragma unroll
    for (int t = 0; t < 22; ++t) {             // 22*256 = 5632 exact
        const int idx = tid + t * 256;
        const int kh = idx >> 9;
        const int j  = (idx >> 5) & 15;
        const int k  = idx & 31;
        const int d  = k - j;
        const float val = (d >= 0 && d < KW) ? w[kh * KW + d] : 0.f;
        bm[idx] = f2b(val);
    }
}

// Zero-barrier 1-wave kernel. Math identical to r11-r20 (verified):
// out[oy0+i][ox0+j] = sum_kh A_kh*B_kh; A_kh[i][k] = X[oy0+kh+i][ox0+k],
// B_kh[k][j] = w[kh][k-j]. A row = lane&15, B col = lane&15,
// C/D col=lane&15,row=(lane>>4)*4+reg.
__global__ __launch_bounds__(64)
void conv2d_1w(const float* __restrict__ x,
               const short* __restrict__ bg,
               const float* __restrict__ bias,
               float* __restrict__ out) {
    __shared__ short tile[TILE_SHORTS];     // 4368 B, wave-private

    const int lane = threadIdx.x;
    const int g    = lane >> 4;
    const int li   = lane & 15;

    // XCD-contiguous mapping (16384 % 8 == 0): xcd owns 8 full column
    // strips; consecutive ids walk DOWN a strip -> vertical halo rows and
    // the adjacent strip stay L2-hot.
    const int id    = (blockIdx.x & 7) * (NBLK / 8) + (blockIdx.x >> 3);
    const int strip = id >> 8;              // 0..63
    const int ty    = id & 255;             // 0..255
    const int gx0   = strip * 64;
    const int gy0   = ty * 16;

    // ---- B fragments -> REGISTERS (issued first; L2-hot after warmup).
    // Static names (rule #20: no runtime-indexed reg arrays).
    const short* bp = bg + li * 32 + g * 8;
#define BLOAD(KH) const bf16x8 B##KH = *reinterpret_cast<const bf16x8*>(bp + (KH) * 512)
    BLOAD(0); BLOAD(1); BLOAD(2); BLOAD(3); BLOAD(4); BLOAD(5);
    BLOAD(6); BLOAD(7); BLOAD(8); BLOAD(9); BLOAD(10);
#undef BLOAD

    // ---- Stage 26x80 band as bf16 (sync, wave-local; no barrier needed) ----
#pragma unroll
    for (int it = 0; it < 9; ++it) {            // ceil(520/64)
        const int i = lane + it * 64;
        if (i < WCHUNK) {
            const int r  = i / NCHW;
            const int c4 = i - r * NCHW;
            const int gy = gy0 + r;
            const int gx = gx0 + c4 * 4;
            float4 v = make_float4(0.f, 0.f, 0.f, 0.f);
            if (gy < IH && gx + 3 < IW) {
                v = *reinterpret_cast<const float4*>(x + (size_t)gy * IW + gx);
            }
            bf16x4 b = { f2b(v.x), f2b(v.y), f2b(v.z), f2b(v.w) };
            *reinterpret_cast<bf16x4*>(&tile[r * TSTRIDE + c4 * 4]) = b;
        }
    }
    // (compiler inserts the wave-local lgkmcnt wait before the first ds_read)

    // ---- Compute: 4 c-tiles x 11 kh, ping-pong pipelined (static names) ----
    f32x4 acc[4] = {};
    const short* ap = &tile[li * TSTRIDE + g * 8];

    bf16x8 Ae[4], Ao[4];
#define LOADA(A, ROW) do {                                                   \
        const short* p_ = ap + (ROW) * TSTRIDE;                              \
        _Pragma("unroll")                                                    \
        for (int c = 0; c < 4; ++c) {                                        \
            bf16x4 lo = *reinterpret_cast<const bf16x4*>(p_ + c * 16);       \
            bf16x4 hi = *reinterpret_cast<const bf16x4*>(p_ + c * 16 + 4);   \
            A[c] = __builtin_shufflevector(lo, hi, 0, 1, 2, 3, 4, 5, 6, 7);  \
        }                                                                    \
    } while (0)
#define MFMA4(A, B) do {                                                     \
        _Pragma("unroll")                                                    \
        for (int c = 0; c < 4; ++c)                                          \
            acc[c] = __builtin_amdgcn_mfma_f32_16x16x32_bf16(A[c], B,        \
                                                             acc[c], 0, 0, 0); \
    } while (0)
    // STEPE consumes Ae while loading Ao (and vice versa); sched_barrier
    // between steps stops cross-step hoisting (r9-proven pattern).
#define STEPE(KH, B) LOADA(Ao, (KH) + 1); MFMA4(Ae, B); \
        __builtin_amdgcn_sched_barrier(0)
#define STEPO(KH, B) LOADA(Ae, (KH) + 1); MFMA4(Ao, B); \
        __builtin_amdgcn_sched_barrier(0)

    LOADA(Ae, 0);
    STEPE(0, B0);  STEPO(1, B1);  STEPE(2, B2);  STEPO(3, B3);
    STEPE(4, B4);  STEPO(5, B5);  STEPE(6, B6);  STEPO(7, B7);
    STEPE(8, B8);  STEPO(9, B9);  MFMA4(Ae, B10);

#undef STEPE
#undef STEPO
#undef MFMA4
#undef LOADA

    // ---- Write back (store-guarded; clamped halo feeds only guarded) ----
    const float bv = bias[0];
#pragma unroll
    for (int c = 0; c < 4; ++c) {
        const int ox = gx0 + c * 16 + li;
        if (ox < OW) {
#pragma unroll
            for (int r = 0; r < 4; ++r) {
                const int oy = gy0 + g * 4 + r;
                if (oy < OH) {
                    out[(size_t)oy * OW + ox] = acc[c][r] + bv;
                }
            }
        }
    }
}

extern "C" void kernel_launch(void* const* d_in, const int* in_sizes, int n_in,
                              void* d_out, int out_size, void* d_ws, size_t ws_size,
                              hipStream_t stream) {
    const float* x    = (const float*)d_in[0];
    const float* w    = (const float*)d_in[1];
    const float* bias = (const float*)d_in[2];
    float* out        = (float*)d_out;
    short* bm         = (short*)d_ws;        // 11264 B of scratch

    build_bmat<<<dim3(1), dim3(256), 0, stream>>>(w, bm);

    dim3 grid(NBLK);      // 16384 one-wave blocks
    dim3 block(64);
    conv2d_1w<<<grid, block, 0, stream>>>(x, bm, bias, out);
}

// Round 22
// 40.434 us; speedup vs baseline: 1.0973x; 1.0973x over previous
//
#include <hip/hip_runtime.h>
#include <hip/hip_bf16.h>

// Problem constants
#define IH 4096
#define IW 4096
#define KH 11
#define KW 11
#define OH (IH - KH + 1)   // 4086
#define OW (IW - KW + 1)   // 4086

// Block tile: 64x64 outputs, 8 waves (512 threads).
// Wave wv -> row band (wv>>1)*16, col half (wv&1)*32 (2 c-tiles of 16).
#define BM 64
#define BN 64
#define TROWS   74               // staged input rows (64 + 10 halo)
#define FSTRIDE 84               // f32/row: 21 x 16B chunks (20 data + 1 pad);
                                 // li*84 mod 32 -> 8 residues = ~2-way reads
#define NCH_ROW 21
#define NCHUNK  (TROWS * NCH_ROW)      // 1554
#define TILE_FLOATS (TROWS * FSTRIDE)  // 6216 f32 = 24864 B
// LDS: 2 x 24864 = 49728 B -> 3 blocks/CU (if VGPR <= 85), else 2

#define TILES_X 64
#define NPAIR   2048             // 2 adjacent-x tiles per block

typedef short bf16x8 __attribute__((ext_vector_type(8)));
typedef float f32x4  __attribute__((ext_vector_type(4)));

__device__ __forceinline__ short f2b(float f) {
    __hip_bfloat16 h = __float2bfloat16(f);   // RNE
    return __builtin_bit_cast(short, h);
}

// ---- setup kernel (r17-r21, verified): banded-Toeplitz B in global ----
// B_kh[k][j] = w[kh][k-j] (banded), stored [kh][j][k]: lane frag = 16B chunk.
__global__ void build_bmat(const float* __restrict__ w, short* __restrict__ bm) {
    const int tid = threadIdx.x;
#pragma unroll
    for (int t = 0; t < 22; ++t) {             // 22*256 = 5632 exact
        const int idx = tid + t * 256;
        const int kh = idx >> 9;
        const int j  = (idx >> 5) & 15;
        const int k  = idx & 31;
        const int d  = k - j;
        const float val = (d >= 0 && d < KW) ? w[kh * KW + d] : 0.f;
        bm[idx] = f2b(val);
    }
}

// True-async chassis: global_load_lds DMA into a double buffer; the next
// tile's DMA is fired IMMEDIATELY after the barrier and lands during the
// current tile's compute (which is LDS-only). No staging VGPRs, no cvt
// burst, no ds_write, no exposed drain — the barrier's auto vmcnt(0) hits
// a DMA that completed under the compute shadow.
// Math identical to r11-r21 (verified): out = sum_kh A_kh*B_kh;
// A_kh[i][k] = X[oy0+kh+i][ox0+k], B_kh[k][j] = w[kh][k-j].
// A row = lane&15, B col = lane&15, C/D col=lane&15,row=(lane>>4)*4+reg.
__global__ __launch_bounds__(512)
void conv2d_async(const float* __restrict__ x,
                  const short* __restrict__ bg,
                  const float* __restrict__ bias,
                  float* __restrict__ out) {
    __shared__ float buf[2][TILE_FLOATS];   // 49728 B

    const int tid = threadIdx.x;
    // XCD-bijective swizzle (2048 % 8 == 0): each XCD gets 256 contiguous
    // pairs = 8 full tile rows -> halo re-reads hit the same L2.
    const int pair = (blockIdx.x & 7) * (NPAIR / 8) + (blockIdx.x >> 3);
    const int t0   = pair * 2;               // even -> t0,t0+1 share a row
    const int gy0  = (t0 >> 6) * BM;
    const int gxb  = (t0 & (TILES_X - 1)) * BN;

    const int lane = tid & 63;
    const int wvb  = tid & ~63;     // wave-uniform chunk base
    const int wv   = tid >> 6;      // 0..7
    const int wr   = wv >> 1;       // row band 0..3
    const int ch   = wv & 1;        // col half 0..1
    const int g    = lane >> 4;
    const int li   = lane & 15;
    const float bv = bias[0];

    // ---- B fragments -> registers (L2-hot after warmup; static names) ----
    const short* bp = bg + li * 32 + g * 8;
#define BLOAD(K) const bf16x8 B##K = *reinterpret_cast<const bf16x8*>(bp + (K) * 512)
    BLOAD(0); BLOAD(1); BLOAD(2); BLOAD(3); BLOAD(4); BLOAD(5);
    BLOAD(6); BLOAD(7); BLOAD(8); BLOAD(9); BLOAD(10);
#undef BLOAD

    // ---- DMA staging: chunk i -> LDS 16B slot i; per-lane clamped SOURCE.
    // Clamped (garbage) rows/cols feed only store-guarded outputs (r20-
    // verified). Dest = wave-uniform base + lane*16 (DMA requirement). ----
#define DMAST(BI, GX0) do {                                                  \
        _Pragma("unroll")                                                    \
        for (int it_ = 0; it_ < 4; ++it_) {                                  \
            const int i_ = tid + it_ * 512;                                  \
            if (i_ < NCHUNK) {                                               \
                const int r_  = i_ / NCH_ROW;                                \
                const int c4_ = i_ - r_ * NCH_ROW;                           \
                const int gy_ = gy0 + r_;                                    \
                const int gx_ = (GX0) + c4_ * 4;                             \
                const float* s_ = (c4_ < 20 && gy_ < IH && gx_ + 3 < IW)     \
                                  ? (x + (size_t)gy_ * IW + gx_) : x;        \
                __builtin_amdgcn_global_load_lds(                            \
                    (const __attribute__((address_space(1))) void*)s_,      \
                    (__attribute__((address_space(3))) void*)                \
                        &buf[BI][(it_ * 512 + wvb) * 4],                     \
                    16, 0, 0);                                               \
            }                                                                \
        }                                                                    \
    } while (0)

    // ---- A-frag: 2x b128 f32 + cvt (RNE, r20-verified numerics) ----
#define LOADA(A, ROW) do {                                                   \
        _Pragma("unroll")                                                    \
        for (int c_ = 0; c_ < 2; ++c_) {                                     \
            f32x4 p_ = *reinterpret_cast<const f32x4*>(ap + (ROW) * FSTRIDE + c_ * 16);     \
            f32x4 q_ = *reinterpret_cast<const f32x4*>(ap + (ROW) * FSTRIDE + c_ * 16 + 4); \
            bf16x8 v_;                                                       \
            _Pragma("unroll")                                                \
            for (int e_ = 0; e_ < 4; ++e_) {                                 \
                v_[e_] = f2b(p_[e_]); v_[4 + e_] = f2b(q_[e_]);              \
            }                                                                \
            A[c_] = v_;                                                      \
        }                                                                    \
    } while (0)
#define MFMA2(A, BF) do {                                                    \
        _Pragma("unroll")                                                    \
        for (int c_ = 0; c_ < 2; ++c_)                                       \
            acc[c_] = __builtin_amdgcn_mfma_f32_16x16x32_bf16(A[c_], (BF),   \
                                                              acc[c_], 0, 0, 0); \
    } while (0)
    // Ping-pong steps with per-step sched_barrier (r9/r21 pattern: stops
    // cross-step hoisting -> bounds the live set).
#define STEPE(K, BF) LOADA(Ao, (K) + 1); MFMA2(Ae, BF); \
        __builtin_amdgcn_sched_barrier(0)
#define STEPO(K, BF) LOADA(Ae, (K) + 1); MFMA2(Ao, BF); \
        __builtin_amdgcn_sched_barrier(0)

#define COMPUTE(BI, GX0) do {                                                \
        f32x4 acc[2] = {};                                                   \
        const float* ap = &buf[BI][(16 * wr + li) * FSTRIDE + ch * 32 + g * 8]; \
        bf16x8 Ae[2], Ao[2];                                                 \
        LOADA(Ae, 0);                                                        \
        STEPE(0, B0); STEPO(1, B1); STEPE(2, B2); STEPO(3, B3);              \
        STEPE(4, B4); STEPO(5, B5); STEPE(6, B6); STEPO(7, B7);              \
        STEPE(8, B8); STEPO(9, B9); MFMA2(Ae, B10);                          \
        _Pragma("unroll")                                                    \
        for (int c_ = 0; c_ < 2; ++c_) {                                     \
            const int ox_ = (GX0) + ch * 32 + c_ * 16 + li;                  \
            if (ox_ < OW) {                                                  \
                _Pragma("unroll")                                            \
                for (int r_ = 0; r_ < 4; ++r_) {                             \
                    const int oy_ = gy0 + wr * 16 + g * 4 + r_;              \
                    if (oy_ < OH)                                            \
                        out[(size_t)oy_ * OW + ox_] = acc[c_][r_] + bv;      \
                }                                                            \
            }                                                                \
        }                                                                    \
    } while (0)

    // ---- Pipeline: DMA0 | bar | DMA1 + compute0 | bar | compute1 ----
    DMAST(0, gxb);
    __syncthreads();                 // drain DMA0 (+ B-loads on first use)

    DMAST(1, gxb + BN);              // flies under compute 0
    COMPUTE(0, gxb);
    __syncthreads();                 // DMA1 already landed; publishes buf[1]

    COMPUTE(1, gxb + BN);

#undef COMPUTE
#undef STEPO
#undef STEPE
#undef MFMA2
#undef LOADA
#undef DMAST
}

extern "C" void kernel_launch(void* const* d_in, const int* in_sizes, int n_in,
                              void* d_out, int out_size, void* d_ws, size_t ws_size,
                              hipStream_t stream) {
    const float* x    = (const float*)d_in[0];
    const float* w    = (const float*)d_in[1];
    const float* bias = (const float*)d_in[2];
    float* out        = (float*)d_out;
    short* bm         = (short*)d_ws;        // 11264 B of scratch

    build_bmat<<<dim3(1), dim3(256), 0, stream>>>(w, bm);

    dim3 grid(NPAIR);     // 2048 blocks x 2 tiles
    dim3 block(512);
    conv2d_async<<<grid, block, 0, stream>>>(x, bm, bias, out);
}